// Round 3
// baseline (1778.011 us; speedup 1.0000x reference)
//
#include <hip/hip_runtime.h>
#include <hip/hip_bf16.h>
#include <math.h>

#define N_NODES 100000
#define N_EDGES 3200000
#define IN_DIM  512
#define HID     256
#define NBUCK   ((N_NODES + 127) >> 7)   // 782 buckets of 128 rows

typedef __attribute__((ext_vector_type(8))) short bf16x8;
typedef __attribute__((ext_vector_type(4))) float f32x4;

__device__ __forceinline__ ushort f2bf(float f) {
  uint x = __float_as_uint(f);
  return (ushort)((x + 0x7fffu + ((x >> 16) & 1u)) >> 16);
}
__device__ __forceinline__ float bf2f(ushort u) {
  return __uint_as_float(((uint)u) << 16);
}

// ---------------------------------------------------------------------------
// K0: Wfused = W2 @ fc1_W  [256x32], bfused = b2 @ fc1_W + fc1_b  [32]
__global__ __launch_bounds__(256) void fuse_weights(
    const float* __restrict__ W2, const float* __restrict__ fc1W,
    const float* __restrict__ b2, const float* __restrict__ fc1b,
    float* __restrict__ Wf, float* __restrict__ bf) {
  int tid = threadIdx.x;
  int i = blockIdx.x * 32 + (tid >> 3);
  int jg = (tid & 7) * 4;
  float4 acc = {0.f, 0.f, 0.f, 0.f};
  for (int k = 0; k < HID; k++) {
    float w = W2[i * HID + k];
    float4 f = *(const float4*)(fc1W + k * 32 + jg);
    acc.x += w * f.x; acc.y += w * f.y; acc.z += w * f.z; acc.w += w * f.w;
  }
  *(float4*)(Wf + i * 32 + jg) = acc;
  if (blockIdx.x == 0 && tid < 32) {
    float s = fc1b[tid];
    for (int k = 0; k < HID; k++) s += b2[k] * fc1W[k * 32 + tid];
    bf[tid] = s;
  }
}

// ---------------------------------------------------------------------------
// K0b: W1T_bf16[n][k] = bf16(W1[k][n])
__global__ __launch_bounds__(256) void prep_w1t(
    const float* __restrict__ W1, ushort* __restrict__ W1T) {
  int n = blockIdx.x;
  for (int k = threadIdx.x; k < IN_DIM; k += 256)
    W1T[(size_t)n * IN_DIM + k] = f2bf(W1[(size_t)k * HID + n]);
}

// ---------------------------------------------------------------------------
// K1: histogram of edge destination rows
__global__ __launch_bounds__(256) void hist_kernel(
    const int* __restrict__ rows, int* __restrict__ cnt, int n) {
  int i = blockIdx.x * 256 + threadIdx.x;
  if (i < n) atomicAdd(&cnt[rows[i]], 1);
}

// ---------------------------------------------------------------------------
// K2a: per-block sums of cnt
__global__ __launch_bounds__(256) void blocksum_kernel(
    const int* __restrict__ cnt, int* __restrict__ bsum, int n) {
  int i = blockIdx.x * 256 + threadIdx.x;
  int v = (i < n) ? cnt[i] : 0;
  #pragma unroll
  for (int m = 1; m < 64; m <<= 1) v += __shfl_xor(v, m, 64);
  __shared__ int ws[4];
  if ((threadIdx.x & 63) == 0) ws[threadIdx.x >> 6] = v;
  __syncthreads();
  if (threadIdx.x == 0) bsum[blockIdx.x] = ws[0] + ws[1] + ws[2] + ws[3];
}

// K2b: exclusive scan of <=512 block sums
__global__ __launch_bounds__(512) void scanpart_kernel(
    int* __restrict__ bsum, int nb) {
  int tid = threadIdx.x, lane = tid & 63, wid = tid >> 6;
  int v = (tid < nb) ? bsum[tid] : 0;
  int x = v;
  #pragma unroll
  for (int d = 1; d < 64; d <<= 1) {
    int y = __shfl_up(x, d, 64);
    if (lane >= d) x += y;
  }
  __shared__ int ws[8];
  if (lane == 63) ws[wid] = x;
  __syncthreads();
  int woff = 0;
  for (int w = 0; w < wid; w++) woff += ws[w];
  if (tid < nb) bsum[tid] = woff + x - v;
}

// K2c: rowptr = bsum[block] + in-block exclusive scan
__global__ __launch_bounds__(256) void scanfinal_kernel(
    const int* __restrict__ cnt, const int* __restrict__ bsum,
    int* __restrict__ rowptr, int n) {
  int tid = threadIdx.x, lane = tid & 63, wid = tid >> 6;
  int i = blockIdx.x * 256 + tid;
  int v = (i < n) ? cnt[i] : 0;
  int x = v;
  #pragma unroll
  for (int d = 1; d < 64; d <<= 1) {
    int y = __shfl_up(x, d, 64);
    if (lane >= d) x += y;
  }
  __shared__ int ws[4];
  if (lane == 63) ws[wid] = x;
  __syncthreads();
  int woff = bsum[blockIdx.x];
  for (int w = 0; w < wid; w++) woff += ws[w];
  int excl = woff + x - v;
  if (i < n) rowptr[i] = excl;
  if (i == 0) rowptr[n] = N_EDGES;
}

// ---------------------------------------------------------------------------
// K3a: bucket cursors = rowptr at bucket base
__global__ __launch_bounds__(256) void bcur_init(
    const int* __restrict__ rowptr, int* __restrict__ bcur) {
  int b = blockIdx.x * 256 + threadIdx.x;
  if (b < NBUCK) bcur[b] = rowptr[b << 7];
}

// K3b: phase-1 scatter into bucket-grouped temp (writes cluster per bucket)
__global__ __launch_bounds__(256) void scatter_p1(
    const int* __restrict__ rows, const int* __restrict__ cols,
    const float* __restrict__ vals, int* __restrict__ bcur,
    int2* __restrict__ tcv, int* __restrict__ trow, int n) {
  int i = blockIdx.x * 256 + threadIdx.x;
  if (i < n) {
    int r = rows[i];
    int p = atomicAdd(&bcur[r >> 7], 1);
    int2 e; e.x = cols[i]; e.y = __float_as_int(vals[i]);
    tcv[p] = e;
    trow[p] = r;
  }
}

// K3c: phase-2 per-bucket scatter to final CSR slots (L2-resident window)
__global__ __launch_bounds__(256) void scatter_p2(
    const int* __restrict__ rowptr, const int2* __restrict__ tcv,
    const int* __restrict__ trow, int2* __restrict__ cv) {
  __shared__ int lcur[128];
  int b = blockIdx.x;
  int r0 = b << 7;
  int nr = min(128, N_NODES - r0);
  int tid = threadIdx.x;
  if (tid < nr) lcur[tid] = rowptr[r0 + tid];
  __syncthreads();
  int start = rowptr[r0];
  int end = rowptr[r0 + nr];
  for (int i = start + tid; i < end; i += 256) {
    int r = trow[i];
    int2 e = tcv[i];
    int p = atomicAdd(&lcur[r - r0], 1);
    cv[p] = e;
  }
}

// ---------------------------------------------------------------------------
// K4: S1_bf16 = bf16( X @ W1 )  MFMA 16x16x32 bf16. BM=128 BN=256(full) BK=32.
// X read exactly once (grid.y=1).
__global__ __launch_bounds__(256) void gemm1_mfma(
    const float* __restrict__ A, const ushort* __restrict__ BT,
    ushort* __restrict__ C, int M) {
  __shared__ __align__(16) char smem[65536];
  ushort* As = (ushort*)smem;              // [128][40] bf16
  ushort* Bs = (ushort*)(smem + 10240);    // [256][40] bf16
  int tid = threadIdx.x;
  int bm = blockIdx.x * 128;
  int lane = tid & 63, wid = tid >> 6;
  int waveM = wid >> 1, waveN = wid & 1;
  int l16 = lane & 15, quad = lane >> 4;

  f32x4 acc[4][8] = {};

  int ar = tid >> 1;
  int ac = (tid & 1) * 16;
  const float* aptr = A + (size_t)(bm + ar) * IN_DIM + ac;
  bool avalid = (bm + ar) < M;
  ushort* aw = As + ar * 40 + ac;
  const ushort* bptr = BT + (size_t)tid * IN_DIM;
  ushort* bw = Bs + tid * 40;

  for (int k0 = 0; k0 < IN_DIM; k0 += 32) {
    #pragma unroll
    for (int i = 0; i < 4; i++) {
      float4 av = {0.f, 0.f, 0.f, 0.f};
      if (avalid) av = *(const float4*)(aptr + k0 + i * 4);
      ushort4 p;
      p.x = f2bf(av.x); p.y = f2bf(av.y); p.z = f2bf(av.z); p.w = f2bf(av.w);
      *(ushort4*)(aw + i * 4) = p;
    }
    #pragma unroll
    for (int i = 0; i < 4; i++)
      *(int4*)(bw + i * 8) = *(const int4*)(bptr + k0 + i * 8);
    __syncthreads();

    bf16x8 af[4], bfv[8];
    #pragma unroll
    for (int mi = 0; mi < 4; mi++)
      af[mi] = *(const bf16x8*)(As + (waveM * 64 + mi * 16 + l16) * 40 + quad * 8);
    #pragma unroll
    for (int ni = 0; ni < 8; ni++)
      bfv[ni] = *(const bf16x8*)(Bs + (waveN * 128 + ni * 16 + l16) * 40 + quad * 8);
    #pragma unroll
    for (int mi = 0; mi < 4; mi++)
      #pragma unroll
      for (int ni = 0; ni < 8; ni++)
        acc[mi][ni] = __builtin_amdgcn_mfma_f32_16x16x32_bf16(
            af[mi], bfv[ni], acc[mi][ni], 0, 0, 0);
    __syncthreads();
  }

  // epilogue: LDS repack (aliases staging; last loop iter ended in barrier)
  ushort* Cs = (ushort*)smem;   // [128][256]
  #pragma unroll
  for (int mi = 0; mi < 4; mi++)
    #pragma unroll
    for (int ni = 0; ni < 8; ni++)
      #pragma unroll
      for (int r = 0; r < 4; r++)
        Cs[(waveM * 64 + mi * 16 + quad * 4 + r) * 256 + waveN * 128 + ni * 16 + l16] =
            f2bf(acc[mi][ni][r]);
  __syncthreads();
  #pragma unroll
  for (int i = 0; i < 16; i++) {
    int f = tid + i * 256;          // 0..4095
    int r = f >> 5, v8 = f & 31;
    if (bm + r < M)
      *(int4*)(C + (size_t)(bm + r) * HID + v8 * 8) =
          *(const int4*)(Cs + r * 256 + v8 * 8);
  }
}

// ---------------------------------------------------------------------------
// K5: fused: h = relu(A_sp @ S1 + b1) kept in LDS (fp32);
//     S2 = h @ Wf written directly. 8 waves / 8 rows per block.
__global__ __launch_bounds__(512) void spmm_fused(
    const int* __restrict__ rowptr, const int2* __restrict__ cv,
    const ushort* __restrict__ S, const float* __restrict__ bias,
    const float* __restrict__ Wf, float* __restrict__ S2, int nrows) {
  __shared__ float WfT[32 * 260];   // [j][k], pad 260 -> 4-way b128 conflict max
  __shared__ float hbuf[8][256];
  int tid = threadIdx.x;
  for (int idx = tid; idx < HID * 32; idx += 512) {
    int k = idx >> 5, j = idx & 31;
    WfT[j * 260 + k] = Wf[idx];
  }
  __syncthreads();

  int w = tid >> 6, lane = tid & 63;
  int row = blockIdx.x * 8 + w;
  if (row >= nrows) return;   // grid is exact; never taken
  int start = rowptr[row], end = rowptr[row + 1];
  float a0 = 0.f, a1 = 0.f, a2 = 0.f, a3 = 0.f;
  int j = start;
  for (; j + 1 < end; j += 2) {
    int2 e0 = cv[j];
    int2 e1 = cv[j + 1];
    float v0 = __int_as_float(e0.y);
    float v1 = __int_as_float(e1.y);
    ushort4 s0 = *(const ushort4*)(S + (size_t)e0.x * HID + lane * 4);
    ushort4 s1 = *(const ushort4*)(S + (size_t)e1.x * HID + lane * 4);
    a0 += v0 * bf2f(s0.x); a1 += v0 * bf2f(s0.y);
    a2 += v0 * bf2f(s0.z); a3 += v0 * bf2f(s0.w);
    a0 += v1 * bf2f(s1.x); a1 += v1 * bf2f(s1.y);
    a2 += v1 * bf2f(s1.z); a3 += v1 * bf2f(s1.w);
  }
  if (j < end) {
    int2 e0 = cv[j];
    float v0 = __int_as_float(e0.y);
    ushort4 s0 = *(const ushort4*)(S + (size_t)e0.x * HID + lane * 4);
    a0 += v0 * bf2f(s0.x); a1 += v0 * bf2f(s0.y);
    a2 += v0 * bf2f(s0.z); a3 += v0 * bf2f(s0.w);
  }
  float4 b = *(const float4*)(bias + lane * 4);
  float4 h;
  h.x = fmaxf(a0 + b.x, 0.f);
  h.y = fmaxf(a1 + b.y, 0.f);
  h.z = fmaxf(a2 + b.z, 0.f);
  h.w = fmaxf(a3 + b.w, 0.f);
  *(float4*)(&hbuf[w][lane * 4]) = h;
  // wave-internal LDS producer->consumer; compiler orders via lgkmcnt

  // S2[row][jo] = sum_k h[k] * Wf[k][jo]; half-wave split over k
  int jo = lane & 31;
  int kbase = (lane >> 5) * 128;
  const float* hb = &hbuf[w][kbase];
  const float* wt = &WfT[jo * 260 + kbase];
  float acc = 0.f;
  #pragma unroll
  for (int kk = 0; kk < 32; kk++) {
    float4 hv = *(const float4*)(hb + kk * 4);
    float4 wv = *(const float4*)(wt + kk * 4);
    acc += hv.x * wv.x + hv.y * wv.y + hv.z * wv.z + hv.w * wv.w;
  }
  acc += __shfl_xor(acc, 32, 64);
  if (lane < 32) S2[(size_t)row * 32 + jo] = acc;
}

// ---------------------------------------------------------------------------
// K7: t = A_sp @ S2 + bfused; out = log_softmax(relu(t) @ fc2W + fc2b)
__global__ __launch_bounds__(256) void spmm32_out_kernel(
    const int* __restrict__ rowptr, const int2* __restrict__ cv,
    const float* __restrict__ S2, const float* __restrict__ bf,
    const float* __restrict__ fc2W, const float* __restrict__ fc2b,
    float* __restrict__ out, int nrows) {
  int sub = threadIdx.x >> 5;
  int lane32 = threadIdx.x & 31;
  int row = blockIdx.x * 8 + sub;
  if (row >= nrows) return;
  int start = rowptr[row], end = rowptr[row + 1];
  float acc = 0.f;
  int j = start;
  for (; j + 1 < end; j += 2) {
    int2 e0 = cv[j];
    int2 e1 = cv[j + 1];
    float s0 = S2[(size_t)e0.x * 32 + lane32];
    float s1 = S2[(size_t)e1.x * 32 + lane32];
    acc += __int_as_float(e0.y) * s0;
    acc += __int_as_float(e1.y) * s1;
  }
  if (j < end) {
    int2 e0 = cv[j];
    acc += __int_as_float(e0.y) * S2[(size_t)e0.x * 32 + lane32];
  }
  float h = fmaxf(acc + bf[lane32], 0.f);
  float z0p = h * fc2W[lane32 * 2 + 0];
  float z1p = h * fc2W[lane32 * 2 + 1];
  #pragma unroll
  for (int m = 16; m >= 1; m >>= 1) {
    z0p += __shfl_xor(z0p, m, 32);
    z1p += __shfl_xor(z1p, m, 32);
  }
  if (lane32 == 0) {
    float z0 = z0p + fc2b[0];
    float z1 = z1p + fc2b[1];
    float mx = fmaxf(z0, z1);
    float lse = mx + logf(expf(z0 - mx) + expf(z1 - mx));
    float2 o = {z0 - lse, z1 - lse};
    *(float2*)(out + (size_t)row * 2) = o;
  }
}

// ---------------------------------------------------------------------------
extern "C" void kernel_launch(void* const* d_in, const int* in_sizes, int n_in,
                              void* d_out, int out_size, void* d_ws, size_t ws_size,
                              hipStream_t stream) {
  const float* X     = (const float*)d_in[0];
  const int*   erow  = (const int*)d_in[1];
  const int*   ecol  = (const int*)d_in[2];
  const float* eval_ = (const float*)d_in[3];
  const float* W1    = (const float*)d_in[4];
  const float* b1    = (const float*)d_in[5];
  const float* W2    = (const float*)d_in[6];
  const float* b2    = (const float*)d_in[7];
  const float* fc1W  = (const float*)d_in[8];
  const float* fc1b  = (const float*)d_in[9];
  const float* fc2W  = (const float*)d_in[10];
  const float* fc2b  = (const float*)d_in[11];
  float* out = (float*)d_out;

  size_t off = 0;
  auto alloc = [&](size_t bytes) {
    void* p = (char*)d_ws + off;
    off += (bytes + 255) & ~(size_t)255;
    return p;
  };
  float*  Wf     = (float*)alloc((size_t)HID * 32 * 4);
  float*  bf     = (float*)alloc(32 * 4);
  int*    cnt    = (int*)alloc((size_t)N_NODES * 4);
  int*    rowptr = (int*)alloc((size_t)(N_NODES + 1) * 4);
  int*    bsum   = (int*)alloc((size_t)512 * 4);
  int*    bcur   = (int*)alloc((size_t)NBUCK * 4);
  int2*   cv     = (int2*)alloc((size_t)N_EDGES * 8);
  int2*   tcv    = (int2*)alloc((size_t)N_EDGES * 8);
  int*    trow   = (int*)alloc((size_t)N_EDGES * 4);
  ushort* W1T    = (ushort*)alloc((size_t)HID * IN_DIM * 2);
  ushort* S1b    = (ushort*)alloc((size_t)N_NODES * HID * 2);
  float*  S2     = (float*)alloc((size_t)N_NODES * 32 * 4);
  (void)ws_size; (void)n_in; (void)in_sizes; (void)out_size;

  const int NBLK = (N_NODES + 255) / 256;   // 391

  hipMemsetAsync(cnt, 0, (size_t)N_NODES * 4, stream);

  fuse_weights<<<8, 256, 0, stream>>>(W2, fc1W, b2, fc1b, Wf, bf);
  prep_w1t<<<HID, 256, 0, stream>>>(W1, W1T);

  hist_kernel<<<(N_EDGES + 255) / 256, 256, 0, stream>>>(erow, cnt, N_EDGES);
  blocksum_kernel<<<NBLK, 256, 0, stream>>>(cnt, bsum, N_NODES);
  scanpart_kernel<<<1, 512, 0, stream>>>(bsum, NBLK);
  scanfinal_kernel<<<NBLK, 256, 0, stream>>>(cnt, bsum, rowptr, N_NODES);
  bcur_init<<<(NBUCK + 255) / 256, 256, 0, stream>>>(rowptr, bcur);
  scatter_p1<<<(N_EDGES + 255) / 256, 256, 0, stream>>>(
      erow, ecol, eval_, bcur, tcv, trow, N_EDGES);
  scatter_p2<<<NBUCK, 256, 0, stream>>>(rowptr, tcv, trow, cv);

  gemm1_mfma<<<(N_NODES + 127) / 128, 256, 0, stream>>>(X, W1T, S1b, N_NODES);

  spmm_fused<<<(N_NODES + 7) / 8, 512, 0, stream>>>(
      rowptr, cv, S1b, b1, Wf, S2, N_NODES);

  spmm32_out_kernel<<<(N_NODES + 7) / 8, 256, 0, stream>>>(
      rowptr, cv, S2, bf, fc2W, fc2b, out, N_NODES);
}

// Round 4
// 1163.739 us; speedup vs baseline: 1.5278x; 1.5278x over previous
//
#include <hip/hip_runtime.h>
#include <hip/hip_bf16.h>
#include <math.h>

#define N_NODES 100000
#define N_EDGES 3200000
#define IN_DIM  512
#define HID     256

#define NB8     8          // XCD-aligned row buckets
#define ROWS_PB 12500      // rows per bucket (100000/8)
#define BCAP    420000     // slots per bucket region (~400k +/- 0.6k actual; 33 sigma slack)
#define CHUNK   4096       // edges per phase-1 workgroup
#define NSLICE  96         // phase-2 slices per bucket

typedef __attribute__((ext_vector_type(8))) short bf16x8;
typedef __attribute__((ext_vector_type(4))) float f32x4;

__device__ __forceinline__ ushort f2bf(float f) {
  uint x = __float_as_uint(f);
  return (ushort)((x + 0x7fffu + ((x >> 16) & 1u)) >> 16);
}
__device__ __forceinline__ float bf2f(ushort u) {
  return __uint_as_float(((uint)u) << 16);
}

// ---------------------------------------------------------------------------
// K0: Wfused = W2 @ fc1_W  [256x32], bfused = b2 @ fc1_W + fc1_b  [32]
__global__ __launch_bounds__(256) void fuse_weights(
    const float* __restrict__ W2, const float* __restrict__ fc1W,
    const float* __restrict__ b2, const float* __restrict__ fc1b,
    float* __restrict__ Wf, float* __restrict__ bf) {
  int tid = threadIdx.x;
  int i = blockIdx.x * 32 + (tid >> 3);
  int jg = (tid & 7) * 4;
  float4 acc = {0.f, 0.f, 0.f, 0.f};
  for (int k = 0; k < HID; k++) {
    float w = W2[i * HID + k];
    float4 f = *(const float4*)(fc1W + k * 32 + jg);
    acc.x += w * f.x; acc.y += w * f.y; acc.z += w * f.z; acc.w += w * f.w;
  }
  *(float4*)(Wf + i * 32 + jg) = acc;
  if (blockIdx.x == 0 && tid < 32) {
    float s = fc1b[tid];
    for (int k = 0; k < HID; k++) s += b2[k] * fc1W[k * 32 + tid];
    bf[tid] = s;
  }
}

// ---------------------------------------------------------------------------
// K0b: W1T_bf16[n][k] = bf16(W1[k][n])
__global__ __launch_bounds__(256) void prep_w1t(
    const float* __restrict__ W1, ushort* __restrict__ W1T) {
  int n = blockIdx.x;
  for (int k = threadIdx.x; k < IN_DIM; k += 256)
    W1T[(size_t)n * IN_DIM + k] = f2bf(W1[(size_t)k * HID + n]);
}

// ---------------------------------------------------------------------------
// K1: histogram of edge destination rows
__global__ __launch_bounds__(256) void hist_kernel(
    const int* __restrict__ rows, int* __restrict__ cnt, int n) {
  int i = blockIdx.x * 256 + threadIdx.x;
  if (i < n) atomicAdd(&cnt[rows[i]], 1);
}

// ---------------------------------------------------------------------------
// K2a: per-block sums of cnt
__global__ __launch_bounds__(256) void blocksum_kernel(
    const int* __restrict__ cnt, int* __restrict__ bsum, int n) {
  int i = blockIdx.x * 256 + threadIdx.x;
  int v = (i < n) ? cnt[i] : 0;
  #pragma unroll
  for (int m = 1; m < 64; m <<= 1) v += __shfl_xor(v, m, 64);
  __shared__ int ws[4];
  if ((threadIdx.x & 63) == 0) ws[threadIdx.x >> 6] = v;
  __syncthreads();
  if (threadIdx.x == 0) bsum[blockIdx.x] = ws[0] + ws[1] + ws[2] + ws[3];
}

// K2b: exclusive scan of <=512 block sums
__global__ __launch_bounds__(512) void scanpart_kernel(
    int* __restrict__ bsum, int nb) {
  int tid = threadIdx.x, lane = tid & 63, wid = tid >> 6;
  int v = (tid < nb) ? bsum[tid] : 0;
  int x = v;
  #pragma unroll
  for (int d = 1; d < 64; d <<= 1) {
    int y = __shfl_up(x, d, 64);
    if (lane >= d) x += y;
  }
  __shared__ int ws[8];
  if (lane == 63) ws[wid] = x;
  __syncthreads();
  int woff = 0;
  for (int w = 0; w < wid; w++) woff += ws[w];
  if (tid < nb) bsum[tid] = woff + x - v;
}

// K2c: rowptr + cursor = bsum[block] + in-block exclusive scan
__global__ __launch_bounds__(256) void scanfinal_kernel(
    const int* __restrict__ cnt, const int* __restrict__ bsum,
    int* __restrict__ rowptr, int* __restrict__ cursor, int n) {
  int tid = threadIdx.x, lane = tid & 63, wid = tid >> 6;
  int i = blockIdx.x * 256 + tid;
  int v = (i < n) ? cnt[i] : 0;
  int x = v;
  #pragma unroll
  for (int d = 1; d < 64; d <<= 1) {
    int y = __shfl_up(x, d, 64);
    if (lane >= d) x += y;
  }
  __shared__ int ws[4];
  if (lane == 63) ws[wid] = x;
  __syncthreads();
  int woff = bsum[blockIdx.x];
  for (int w = 0; w < wid; w++) woff += ws[w];
  int excl = woff + x - v;
  if (i < n) { rowptr[i] = excl; cursor[i] = excl; }
  if (i == 0) rowptr[n] = N_EDGES;
}

// ---------------------------------------------------------------------------
// K3a: bucket cursors = fixed-capacity region bases
__global__ __launch_bounds__(64) void bcur8_init(int* __restrict__ bcur8) {
  int b = threadIdx.x;
  if (b < NB8) bcur8[b] = b * BCAP;
}

// K3b: phase-1 — bin edges into 8 XCD-aligned row-range buckets.
// Per-workgroup LDS counting + ONE global atomic per bucket per workgroup
// (no hot-cursor contention), then dense burst appends (~6 KB/bucket/wg,
// write amplification ~1).
__global__ __launch_bounds__(256) void scatter_p1(
    const int* __restrict__ rows, const int* __restrict__ cols,
    const float* __restrict__ vals, int* __restrict__ bcur8,
    int2* __restrict__ tcv, int* __restrict__ trow, int n) {
  __shared__ int bcnt[NB8];
  __shared__ int bcur[NB8];
  int tid = threadIdx.x;
  int chunk0 = blockIdx.x * CHUNK;
  if (tid < NB8) bcnt[tid] = 0;
  __syncthreads();

  int r[16], c[16], b[16];
  float v[16];
  #pragma unroll
  for (int i = 0; i < 16; i++) {
    int idx = chunk0 + i * 256 + tid;
    if (idx < n) {
      r[i] = rows[idx];
      c[i] = cols[idx];
      v[i] = vals[idx];
      b[i] = r[i] / ROWS_PB;        // 0..7, compiler magic-div
      atomicAdd(&bcnt[b[i]], 1);
    } else {
      b[i] = -1;
    }
  }
  __syncthreads();
  if (tid < NB8) bcur[tid] = atomicAdd(&bcur8[tid], bcnt[tid]);
  __syncthreads();
  #pragma unroll
  for (int i = 0; i < 16; i++) {
    if (b[i] >= 0) {
      int p = atomicAdd(&bcur[b[i]], 1);
      trow[p] = r[i];
      int2 e; e.x = c[i]; e.y = __float_as_int(v[i]);
      tcv[p] = e;
    }
  }
}

// K3c: phase-2 — scatter bucket b's edges into final CSR. blockIdx&7 == b
// pins all writers of a bucket to one XCD (round-robin heuristic), so the
// 3.2 MB cv window is written from a single L2 -> each line evicted once.
__global__ __launch_bounds__(256) void scatter_p2(
    const int* __restrict__ bcur8, const int2* __restrict__ tcv,
    const int* __restrict__ trow, int* __restrict__ cursor,
    int2* __restrict__ cv) {
  int b = blockIdx.x & 7;
  int s = blockIdx.x >> 3;
  int base = b * BCAP;
  int ecnt = bcur8[b] - base;
  int per = (ecnt + NSLICE - 1) / NSLICE;
  int lo = s * per;
  int hi = min(ecnt, lo + per);
  for (int i = base + lo + threadIdx.x; i < base + hi; i += 256) {
    int r = trow[i];
    int2 e = tcv[i];
    int p = atomicAdd(&cursor[r], 1);
    cv[p] = e;
  }
}

// ---------------------------------------------------------------------------
// K4: S1_bf16 = bf16( X @ W1 )  MFMA 16x16x32 bf16. BM=128 BN=256 BK=32.
__global__ __launch_bounds__(256) void gemm1_mfma(
    const float* __restrict__ A, const ushort* __restrict__ BT,
    ushort* __restrict__ C, int M) {
  __shared__ __align__(16) char smem[65536];
  ushort* As = (ushort*)smem;              // [128][40]
  ushort* Bs = (ushort*)(smem + 10240);    // [256][40]
  int tid = threadIdx.x;
  int bm = blockIdx.x * 128;
  int lane = tid & 63, wid = tid >> 6;
  int waveM = wid >> 1, waveN = wid & 1;
  int l16 = lane & 15, quad = lane >> 4;

  f32x4 acc[4][8] = {};

  int ar = tid >> 1;
  int ac = (tid & 1) * 16;
  const float* aptr = A + (size_t)(bm + ar) * IN_DIM + ac;
  bool avalid = (bm + ar) < M;
  ushort* aw = As + ar * 40 + ac;
  const ushort* bptr = BT + (size_t)tid * IN_DIM;
  ushort* bw = Bs + tid * 40;

  for (int k0 = 0; k0 < IN_DIM; k0 += 32) {
    #pragma unroll
    for (int i = 0; i < 4; i++) {
      float4 av = {0.f, 0.f, 0.f, 0.f};
      if (avalid) av = *(const float4*)(aptr + k0 + i * 4);
      ushort4 p;
      p.x = f2bf(av.x); p.y = f2bf(av.y); p.z = f2bf(av.z); p.w = f2bf(av.w);
      *(ushort4*)(aw + i * 4) = p;
    }
    #pragma unroll
    for (int i = 0; i < 4; i++)
      *(int4*)(bw + i * 8) = *(const int4*)(bptr + k0 + i * 8);
    __syncthreads();

    bf16x8 af[4], bfv[8];
    #pragma unroll
    for (int mi = 0; mi < 4; mi++)
      af[mi] = *(const bf16x8*)(As + (waveM * 64 + mi * 16 + l16) * 40 + quad * 8);
    #pragma unroll
    for (int ni = 0; ni < 8; ni++)
      bfv[ni] = *(const bf16x8*)(Bs + (waveN * 128 + ni * 16 + l16) * 40 + quad * 8);
    #pragma unroll
    for (int mi = 0; mi < 4; mi++)
      #pragma unroll
      for (int ni = 0; ni < 8; ni++)
        acc[mi][ni] = __builtin_amdgcn_mfma_f32_16x16x32_bf16(
            af[mi], bfv[ni], acc[mi][ni], 0, 0, 0);
    __syncthreads();
  }

  ushort* Cs = (ushort*)smem;   // [128][256]
  #pragma unroll
  for (int mi = 0; mi < 4; mi++)
    #pragma unroll
    for (int ni = 0; ni < 8; ni++)
      #pragma unroll
      for (int r = 0; r < 4; r++)
        Cs[(waveM * 64 + mi * 16 + quad * 4 + r) * 256 + waveN * 128 + ni * 16 + l16] =
            f2bf(acc[mi][ni][r]);
  __syncthreads();
  #pragma unroll
  for (int i = 0; i < 16; i++) {
    int f = tid + i * 256;
    int r = f >> 5, v8 = f & 31;
    if (bm + r < M)
      *(int4*)(C + (size_t)(bm + r) * HID + v8 * 8) =
          *(const int4*)(Cs + r * 256 + v8 * 8);
  }
}

// ---------------------------------------------------------------------------
// K5: fused: h = relu(A_sp @ S1 + b1) in LDS (fp32); S2 = h @ Wf direct.
__global__ __launch_bounds__(512) void spmm_fused(
    const int* __restrict__ rowptr, const int2* __restrict__ cv,
    const ushort* __restrict__ S, const float* __restrict__ bias,
    const float* __restrict__ Wf, float* __restrict__ S2, int nrows) {
  __shared__ float WfT[32 * 260];
  __shared__ float hbuf[8][256];
  int tid = threadIdx.x;
  for (int idx = tid; idx < HID * 32; idx += 512) {
    int k = idx >> 5, j = idx & 31;
    WfT[j * 260 + k] = Wf[idx];
  }
  __syncthreads();

  int w = tid >> 6, lane = tid & 63;
  int row = blockIdx.x * 8 + w;
  if (row >= nrows) return;
  int start = rowptr[row], end = rowptr[row + 1];
  float a0 = 0.f, a1 = 0.f, a2 = 0.f, a3 = 0.f;
  int j = start;
  for (; j + 1 < end; j += 2) {
    int2 e0 = cv[j];
    int2 e1 = cv[j + 1];
    float v0 = __int_as_float(e0.y);
    float v1 = __int_as_float(e1.y);
    ushort4 s0 = *(const ushort4*)(S + (size_t)e0.x * HID + lane * 4);
    ushort4 s1 = *(const ushort4*)(S + (size_t)e1.x * HID + lane * 4);
    a0 += v0 * bf2f(s0.x); a1 += v0 * bf2f(s0.y);
    a2 += v0 * bf2f(s0.z); a3 += v0 * bf2f(s0.w);
    a0 += v1 * bf2f(s1.x); a1 += v1 * bf2f(s1.y);
    a2 += v1 * bf2f(s1.z); a3 += v1 * bf2f(s1.w);
  }
  if (j < end) {
    int2 e0 = cv[j];
    float v0 = __int_as_float(e0.y);
    ushort4 s0 = *(const ushort4*)(S + (size_t)e0.x * HID + lane * 4);
    a0 += v0 * bf2f(s0.x); a1 += v0 * bf2f(s0.y);
    a2 += v0 * bf2f(s0.z); a3 += v0 * bf2f(s0.w);
  }
  float4 b = *(const float4*)(bias + lane * 4);
  float4 h;
  h.x = fmaxf(a0 + b.x, 0.f);
  h.y = fmaxf(a1 + b.y, 0.f);
  h.z = fmaxf(a2 + b.z, 0.f);
  h.w = fmaxf(a3 + b.w, 0.f);
  *(float4*)(&hbuf[w][lane * 4]) = h;

  int jo = lane & 31;
  int kbase = (lane >> 5) * 128;
  const float* hb = &hbuf[w][kbase];
  const float* wt = &WfT[jo * 260 + kbase];
  float acc = 0.f;
  #pragma unroll
  for (int kk = 0; kk < 32; kk++) {
    float4 hv = *(const float4*)(hb + kk * 4);
    float4 wv = *(const float4*)(wt + kk * 4);
    acc += hv.x * wv.x + hv.y * wv.y + hv.z * wv.z + hv.w * wv.w;
  }
  acc += __shfl_xor(acc, 32, 64);
  if (lane < 32) S2[(size_t)row * 32 + jo] = acc;
}

// ---------------------------------------------------------------------------
// K7: t = A_sp @ S2 + bfused; out = log_softmax(relu(t) @ fc2W + fc2b)
__global__ __launch_bounds__(256) void spmm32_out_kernel(
    const int* __restrict__ rowptr, const int2* __restrict__ cv,
    const float* __restrict__ S2, const float* __restrict__ bf,
    const float* __restrict__ fc2W, const float* __restrict__ fc2b,
    float* __restrict__ out, int nrows) {
  int sub = threadIdx.x >> 5;
  int lane32 = threadIdx.x & 31;
  int row = blockIdx.x * 8 + sub;
  if (row >= nrows) return;
  int start = rowptr[row], end = rowptr[row + 1];
  float acc = 0.f;
  int j = start;
  for (; j + 1 < end; j += 2) {
    int2 e0 = cv[j];
    int2 e1 = cv[j + 1];
    float s0 = S2[(size_t)e0.x * 32 + lane32];
    float s1 = S2[(size_t)e1.x * 32 + lane32];
    acc += __int_as_float(e0.y) * s0;
    acc += __int_as_float(e1.y) * s1;
  }
  if (j < end) {
    int2 e0 = cv[j];
    acc += __int_as_float(e0.y) * S2[(size_t)e0.x * 32 + lane32];
  }
  float h = fmaxf(acc + bf[lane32], 0.f);
  float z0p = h * fc2W[lane32 * 2 + 0];
  float z1p = h * fc2W[lane32 * 2 + 1];
  #pragma unroll
  for (int m = 16; m >= 1; m >>= 1) {
    z0p += __shfl_xor(z0p, m, 32);
    z1p += __shfl_xor(z1p, m, 32);
  }
  if (lane32 == 0) {
    float z0 = z0p + fc2b[0];
    float z1 = z1p + fc2b[1];
    float mx = fmaxf(z0, z1);
    float lse = mx + logf(expf(z0 - mx) + expf(z1 - mx));
    float2 o = {z0 - lse, z1 - lse};
    *(float2*)(out + (size_t)row * 2) = o;
  }
}

// ---------------------------------------------------------------------------
extern "C" void kernel_launch(void* const* d_in, const int* in_sizes, int n_in,
                              void* d_out, int out_size, void* d_ws, size_t ws_size,
                              hipStream_t stream) {
  const float* X     = (const float*)d_in[0];
  const int*   erow  = (const int*)d_in[1];
  const int*   ecol  = (const int*)d_in[2];
  const float* eval_ = (const float*)d_in[3];
  const float* W1    = (const float*)d_in[4];
  const float* b1    = (const float*)d_in[5];
  const float* W2    = (const float*)d_in[6];
  const float* b2    = (const float*)d_in[7];
  const float* fc1W  = (const float*)d_in[8];
  const float* fc1b  = (const float*)d_in[9];
  const float* fc2W  = (const float*)d_in[10];
  const float* fc2b  = (const float*)d_in[11];
  float* out = (float*)d_out;

  size_t off = 0;
  auto alloc = [&](size_t bytes) {
    void* p = (char*)d_ws + off;
    off += (bytes + 255) & ~(size_t)255;
    return p;
  };
  float*  Wf     = (float*)alloc((size_t)HID * 32 * 4);
  float*  bf     = (float*)alloc(32 * 4);
  int*    cnt    = (int*)alloc((size_t)N_NODES * 4);
  int*    rowptr = (int*)alloc((size_t)(N_NODES + 1) * 4);
  int*    cursor = (int*)alloc((size_t)(N_NODES + 1) * 4);
  int*    bsum   = (int*)alloc((size_t)512 * 4);
  int*    bcur8  = (int*)alloc((size_t)64 * 4);
  int2*   cv     = (int2*)alloc((size_t)N_EDGES * 8);
  int2*   tcv    = (int2*)alloc((size_t)NB8 * BCAP * 8);
  int*    trow   = (int*)alloc((size_t)NB8 * BCAP * 4);
  ushort* W1T    = (ushort*)alloc((size_t)HID * IN_DIM * 2);
  ushort* S1b    = (ushort*)alloc((size_t)N_NODES * HID * 2);
  float*  S2     = (float*)alloc((size_t)N_NODES * 32 * 4);
  (void)ws_size; (void)n_in; (void)in_sizes; (void)out_size;

  const int NBLK = (N_NODES + 255) / 256;       // 391
  const int NCHUNK = (N_EDGES + CHUNK - 1) / CHUNK;  // 782

  hipMemsetAsync(cnt, 0, (size_t)N_NODES * 4, stream);

  fuse_weights<<<8, 256, 0, stream>>>(W2, fc1W, b2, fc1b, Wf, bf);
  prep_w1t<<<HID, 256, 0, stream>>>(W1, W1T);

  hist_kernel<<<(N_EDGES + 255) / 256, 256, 0, stream>>>(erow, cnt, N_EDGES);
  blocksum_kernel<<<NBLK, 256, 0, stream>>>(cnt, bsum, N_NODES);
  scanpart_kernel<<<1, 512, 0, stream>>>(bsum, NBLK);
  scanfinal_kernel<<<NBLK, 256, 0, stream>>>(cnt, bsum, rowptr, cursor, N_NODES);
  bcur8_init<<<1, 64, 0, stream>>>(bcur8);
  scatter_p1<<<NCHUNK, 256, 0, stream>>>(
      erow, ecol, eval_, bcur8, tcv, trow, N_EDGES);
  scatter_p2<<<NB8 * NSLICE, 256, 0, stream>>>(bcur8, tcv, trow, cursor, cv);

  gemm1_mfma<<<(N_NODES + 127) / 128, 256, 0, stream>>>(X, W1T, S1b, N_NODES);

  spmm_fused<<<(N_NODES + 7) / 8, 512, 0, stream>>>(
      rowptr, cv, S1b, b1, Wf, S2, N_NODES);

  spmm32_out_kernel<<<(N_NODES + 7) / 8, 256, 0, stream>>>(
      rowptr, cv, S2, bf, fc2W, fc2b, out, N_NODES);
}

// Round 5
// 998.612 us; speedup vs baseline: 1.7805x; 1.1654x over previous
//
#include <hip/hip_runtime.h>
#include <hip/hip_bf16.h>
#include <math.h>

#define N_NODES 100000
#define N_EDGES 3200000
#define IN_DIM  512
#define HID     256

#define NB8     8          // XCD-aligned row buckets
#define ROWS_PB 12500      // rows per bucket
#define BCAP    420000     // slots per bucket region
#define CHUNK   4096       // edges per phase-1 workgroup
#define NSLICE  96         // phase-2 slices per bucket
#define WFT_S   260        // WfT LDS stride in ushorts (520 B row: b64-aligned, 2-way banks)

typedef __attribute__((ext_vector_type(8))) short bf16x8;
typedef __attribute__((ext_vector_type(4))) float f32x4;

__device__ __forceinline__ ushort f2bf(float f) {
  uint x = __float_as_uint(f);
  return (ushort)((x + 0x7fffu + ((x >> 16) & 1u)) >> 16);
}
__device__ __forceinline__ float bf2f(ushort u) {
  return __uint_as_float(((uint)u) << 16);
}

// ---------------------------------------------------------------------------
// K0: WfTb[j][k] = bf16( (W2 @ fc1_W)^T ), bfused = b2 @ fc1_W + fc1_b
__global__ __launch_bounds__(256) void fuse_weights(
    const float* __restrict__ W2, const float* __restrict__ fc1W,
    const float* __restrict__ b2, const float* __restrict__ fc1b,
    ushort* __restrict__ WfTb, float* __restrict__ bf) {
  int tid = threadIdx.x;
  int i = blockIdx.x * 32 + (tid >> 3);   // k index 0..255
  int jg = (tid & 7) * 4;                 // j group
  float4 acc = {0.f, 0.f, 0.f, 0.f};
  for (int k = 0; k < HID; k++) {
    float w = W2[i * HID + k];
    float4 f = *(const float4*)(fc1W + k * 32 + jg);
    acc.x += w * f.x; acc.y += w * f.y; acc.z += w * f.z; acc.w += w * f.w;
  }
  WfTb[(jg + 0) * HID + i] = f2bf(acc.x);
  WfTb[(jg + 1) * HID + i] = f2bf(acc.y);
  WfTb[(jg + 2) * HID + i] = f2bf(acc.z);
  WfTb[(jg + 3) * HID + i] = f2bf(acc.w);
  if (blockIdx.x == 0 && tid < 32) {
    float s = fc1b[tid];
    for (int k = 0; k < HID; k++) s += b2[k] * fc1W[k * 32 + tid];
    bf[tid] = s;
  }
}

// ---------------------------------------------------------------------------
// K0b: W1T_bf16[n][k] = bf16(W1[k][n])
__global__ __launch_bounds__(256) void prep_w1t(
    const float* __restrict__ W1, ushort* __restrict__ W1T) {
  int n = blockIdx.x;
  for (int k = threadIdx.x; k < IN_DIM; k += 256)
    W1T[(size_t)n * IN_DIM + k] = f2bf(W1[(size_t)k * HID + n]);
}

// ---------------------------------------------------------------------------
// K1: histogram of edge destination rows
__global__ __launch_bounds__(256) void hist_kernel(
    const int* __restrict__ rows, int* __restrict__ cnt, int n) {
  int i = blockIdx.x * 256 + threadIdx.x;
  if (i < n) atomicAdd(&cnt[rows[i]], 1);
}

// ---------------------------------------------------------------------------
// K2a: per-block sums of cnt
__global__ __launch_bounds__(256) void blocksum_kernel(
    const int* __restrict__ cnt, int* __restrict__ bsum, int n) {
  int i = blockIdx.x * 256 + threadIdx.x;
  int v = (i < n) ? cnt[i] : 0;
  #pragma unroll
  for (int m = 1; m < 64; m <<= 1) v += __shfl_xor(v, m, 64);
  __shared__ int ws[4];
  if ((threadIdx.x & 63) == 0) ws[threadIdx.x >> 6] = v;
  __syncthreads();
  if (threadIdx.x == 0) bsum[blockIdx.x] = ws[0] + ws[1] + ws[2] + ws[3];
}

// K2b: exclusive scan of <=512 block sums
__global__ __launch_bounds__(512) void scanpart_kernel(
    int* __restrict__ bsum, int nb) {
  int tid = threadIdx.x, lane = tid & 63, wid = tid >> 6;
  int v = (tid < nb) ? bsum[tid] : 0;
  int x = v;
  #pragma unroll
  for (int d = 1; d < 64; d <<= 1) {
    int y = __shfl_up(x, d, 64);
    if (lane >= d) x += y;
  }
  __shared__ int ws[8];
  if (lane == 63) ws[wid] = x;
  __syncthreads();
  int woff = 0;
  for (int w = 0; w < wid; w++) woff += ws[w];
  if (tid < nb) bsum[tid] = woff + x - v;
}

// K2c: rowptr + cursor = bsum[block] + in-block exclusive scan
__global__ __launch_bounds__(256) void scanfinal_kernel(
    const int* __restrict__ cnt, const int* __restrict__ bsum,
    int* __restrict__ rowptr, int* __restrict__ cursor, int n) {
  int tid = threadIdx.x, lane = tid & 63, wid = tid >> 6;
  int i = blockIdx.x * 256 + tid;
  int v = (i < n) ? cnt[i] : 0;
  int x = v;
  #pragma unroll
  for (int d = 1; d < 64; d <<= 1) {
    int y = __shfl_up(x, d, 64);
    if (lane >= d) x += y;
  }
  __shared__ int ws[4];
  if (lane == 63) ws[wid] = x;
  __syncthreads();
  int woff = bsum[blockIdx.x];
  for (int w = 0; w < wid; w++) woff += ws[w];
  int excl = woff + x - v;
  if (i < n) { rowptr[i] = excl; cursor[i] = excl; }
  if (i == 0) rowptr[n] = N_EDGES;
}

// ---------------------------------------------------------------------------
// K3a: bucket cursors = fixed-capacity region bases
__global__ __launch_bounds__(64) void bcur8_init(int* __restrict__ bcur8) {
  int b = threadIdx.x;
  if (b < NB8) bcur8[b] = b * BCAP;
}

// K3b: phase-1 — bin edges into 8 XCD-aligned row-range buckets.
__global__ __launch_bounds__(256) void scatter_p1(
    const int* __restrict__ rows, const int* __restrict__ cols,
    const float* __restrict__ vals, int* __restrict__ bcur8,
    int2* __restrict__ tcv, int* __restrict__ trow, int n) {
  __shared__ int bcnt[NB8];
  __shared__ int bcur[NB8];
  int tid = threadIdx.x;
  int chunk0 = blockIdx.x * CHUNK;
  if (tid < NB8) bcnt[tid] = 0;
  __syncthreads();

  int r[16], c[16], b[16];
  float v[16];
  #pragma unroll
  for (int i = 0; i < 16; i++) {
    int idx = chunk0 + i * 256 + tid;
    if (idx < n) {
      r[i] = rows[idx];
      c[i] = cols[idx];
      v[i] = vals[idx];
      b[i] = r[i] / ROWS_PB;
      atomicAdd(&bcnt[b[i]], 1);
    } else {
      b[i] = -1;
    }
  }
  __syncthreads();
  if (tid < NB8) bcur[tid] = atomicAdd(&bcur8[tid], bcnt[tid]);
  __syncthreads();
  #pragma unroll
  for (int i = 0; i < 16; i++) {
    if (b[i] >= 0) {
      int p = atomicAdd(&bcur[b[i]], 1);
      trow[p] = r[i];
      int2 e; e.x = c[i]; e.y = __float_as_int(v[i]);
      tcv[p] = e;
    }
  }
}

// K3c: phase-2 — per-bucket scatter to final CSR, bucket pinned to XCD.
__global__ __launch_bounds__(256) void scatter_p2(
    const int* __restrict__ bcur8, const int2* __restrict__ tcv,
    const int* __restrict__ trow, int* __restrict__ cursor,
    int2* __restrict__ cv) {
  int b = blockIdx.x & 7;
  int s = blockIdx.x >> 3;
  int base = b * BCAP;
  int ecnt = bcur8[b] - base;
  int per = (ecnt + NSLICE - 1) / NSLICE;
  int lo = s * per;
  int hi = min(ecnt, lo + per);
  for (int i = base + lo + threadIdx.x; i < base + hi; i += 256) {
    int r = trow[i];
    int2 e = tcv[i];
    int p = atomicAdd(&cursor[r], 1);
    cv[p] = e;
  }
}

// ---------------------------------------------------------------------------
// K4: S1_bf16 = bf16( X @ W1 )  MFMA 16x16x32 bf16. BM=128 BN=256 BK=32.
__global__ __launch_bounds__(256) void gemm1_mfma(
    const float* __restrict__ A, const ushort* __restrict__ BT,
    ushort* __restrict__ C, int M) {
  __shared__ __align__(16) char smem[65536];
  ushort* As = (ushort*)smem;              // [128][40]
  ushort* Bs = (ushort*)(smem + 10240);    // [256][40]
  int tid = threadIdx.x;
  int bm = blockIdx.x * 128;
  int lane = tid & 63, wid = tid >> 6;
  int waveM = wid >> 1, waveN = wid & 1;
  int l16 = lane & 15, quad = lane >> 4;

  f32x4 acc[4][8] = {};

  int ar = tid >> 1;
  int ac = (tid & 1) * 16;
  const float* aptr = A + (size_t)(bm + ar) * IN_DIM + ac;
  bool avalid = (bm + ar) < M;
  ushort* aw = As + ar * 40 + ac;
  const ushort* bptr = BT + (size_t)tid * IN_DIM;
  ushort* bw = Bs + tid * 40;

  for (int k0 = 0; k0 < IN_DIM; k0 += 32) {
    #pragma unroll
    for (int i = 0; i < 4; i++) {
      float4 av = {0.f, 0.f, 0.f, 0.f};
      if (avalid) av = *(const float4*)(aptr + k0 + i * 4);
      ushort4 p;
      p.x = f2bf(av.x); p.y = f2bf(av.y); p.z = f2bf(av.z); p.w = f2bf(av.w);
      *(ushort4*)(aw + i * 4) = p;
    }
    #pragma unroll
    for (int i = 0; i < 4; i++)
      *(int4*)(bw + i * 8) = *(const int4*)(bptr + k0 + i * 8);
    __syncthreads();

    bf16x8 af[4], bfv[8];
    #pragma unroll
    for (int mi = 0; mi < 4; mi++)
      af[mi] = *(const bf16x8*)(As + (waveM * 64 + mi * 16 + l16) * 40 + quad * 8);
    #pragma unroll
    for (int ni = 0; ni < 8; ni++)
      bfv[ni] = *(const bf16x8*)(Bs + (waveN * 128 + ni * 16 + l16) * 40 + quad * 8);
    #pragma unroll
    for (int mi = 0; mi < 4; mi++)
      #pragma unroll
      for (int ni = 0; ni < 8; ni++)
        acc[mi][ni] = __builtin_amdgcn_mfma_f32_16x16x32_bf16(
            af[mi], bfv[ni], acc[mi][ni], 0, 0, 0);
    __syncthreads();
  }

  ushort* Cs = (ushort*)smem;   // [128][256]
  #pragma unroll
  for (int mi = 0; mi < 4; mi++)
    #pragma unroll
    for (int ni = 0; ni < 8; ni++)
      #pragma unroll
      for (int r = 0; r < 4; r++)
        Cs[(waveM * 64 + mi * 16 + quad * 4 + r) * 256 + waveN * 128 + ni * 16 + l16] =
            f2bf(acc[mi][ni][r]);
  __syncthreads();
  #pragma unroll
  for (int i = 0; i < 16; i++) {
    int f = tid + i * 256;
    int r = f >> 5, v8 = f & 31;
    if (bm + r < M)
      *(int4*)(C + (size_t)(bm + r) * HID + v8 * 8) =
          *(const int4*)(Cs + r * 256 + v8 * 8);
  }
}

// ---------------------------------------------------------------------------
// K5: fused: h = relu(A_sp @ S1 + b1) in LDS (fp32); S2 = h @ Wf direct.
// LDS 24.6 KB + VGPR<=64 -> 4 blocks/CU (32 waves). Gather unrolled 4x.
__global__ __launch_bounds__(512, 8) void spmm_fused(
    const int* __restrict__ rowptr, const int2* __restrict__ cv,
    const ushort* __restrict__ S, const float* __restrict__ bias,
    const ushort* __restrict__ WfTb, float* __restrict__ S2, int nrows) {
  __shared__ ushort WfT[32 * WFT_S];   // 16.25 KB bf16, [j][k]
  __shared__ float hbuf[8][256];       // 8 KB
  int tid = threadIdx.x;
  for (int idx = tid; idx < 32 * 64; idx += 512) {
    int jj = idx >> 6, kg = idx & 63;
    *(ushort4*)&WfT[jj * WFT_S + kg * 4] = *(const ushort4*)&WfTb[jj * HID + kg * 4];
  }
  __syncthreads();

  int w = tid >> 6, lane = tid & 63;
  int row = blockIdx.x * 8 + w;
  if (row >= nrows) return;
  int start = rowptr[row], end = rowptr[row + 1];
  float a0 = 0.f, a1 = 0.f, a2 = 0.f, a3 = 0.f;
  const ushort* Sl = S + lane * 4;
  int j = start;
  for (; j + 3 < end; j += 4) {
    int2 e0 = cv[j];
    int2 e1 = cv[j + 1];
    int2 e2 = cv[j + 2];
    int2 e3 = cv[j + 3];
    ushort4 s0 = *(const ushort4*)(Sl + (size_t)e0.x * HID);
    ushort4 s1 = *(const ushort4*)(Sl + (size_t)e1.x * HID);
    ushort4 s2 = *(const ushort4*)(Sl + (size_t)e2.x * HID);
    ushort4 s3 = *(const ushort4*)(Sl + (size_t)e3.x * HID);
    float v0 = __int_as_float(e0.y);
    float v1 = __int_as_float(e1.y);
    float v2 = __int_as_float(e2.y);
    float v3 = __int_as_float(e3.y);
    a0 += v0 * bf2f(s0.x); a1 += v0 * bf2f(s0.y);
    a2 += v0 * bf2f(s0.z); a3 += v0 * bf2f(s0.w);
    a0 += v1 * bf2f(s1.x); a1 += v1 * bf2f(s1.y);
    a2 += v1 * bf2f(s1.z); a3 += v1 * bf2f(s1.w);
    a0 += v2 * bf2f(s2.x); a1 += v2 * bf2f(s2.y);
    a2 += v2 * bf2f(s2.z); a3 += v2 * bf2f(s2.w);
    a0 += v3 * bf2f(s3.x); a1 += v3 * bf2f(s3.y);
    a2 += v3 * bf2f(s3.z); a3 += v3 * bf2f(s3.w);
  }
  for (; j < end; j++) {
    int2 e0 = cv[j];
    float v0 = __int_as_float(e0.y);
    ushort4 s0 = *(const ushort4*)(Sl + (size_t)e0.x * HID);
    a0 += v0 * bf2f(s0.x); a1 += v0 * bf2f(s0.y);
    a2 += v0 * bf2f(s0.z); a3 += v0 * bf2f(s0.w);
  }
  float4 b = *(const float4*)(bias + lane * 4);
  float4 h;
  h.x = fmaxf(a0 + b.x, 0.f);
  h.y = fmaxf(a1 + b.y, 0.f);
  h.z = fmaxf(a2 + b.z, 0.f);
  h.w = fmaxf(a3 + b.w, 0.f);
  *(float4*)(&hbuf[w][lane * 4]) = h;
  // same-wave producer->consumer; compiler orders via lgkmcnt

  int jo = lane & 31;
  int kbase = (lane >> 5) * 128;
  const float* hb = &hbuf[w][kbase];
  const ushort* wt = &WfT[jo * WFT_S + kbase];
  float acc = 0.f;
  #pragma unroll
  for (int kk = 0; kk < 32; kk++) {
    float4 hv = *(const float4*)(hb + kk * 4);       // broadcast (free)
    ushort4 wv = *(const ushort4*)(wt + kk * 4);     // b64, <=4-way
    acc += hv.x * bf2f(wv.x) + hv.y * bf2f(wv.y) +
           hv.z * bf2f(wv.z) + hv.w * bf2f(wv.w);
  }
  acc += __shfl_xor(acc, 32, 64);
  if (lane < 32) S2[(size_t)row * 32 + jo] = acc;
}

// ---------------------------------------------------------------------------
// K7: t = A_sp @ S2 + bfused; out = log_softmax(relu(t) @ fc2W + fc2b)
__global__ __launch_bounds__(256) void spmm32_out_kernel(
    const int* __restrict__ rowptr, const int2* __restrict__ cv,
    const float* __restrict__ S2, const float* __restrict__ bf,
    const float* __restrict__ fc2W, const float* __restrict__ fc2b,
    float* __restrict__ out, int nrows) {
  int sub = threadIdx.x >> 5;
  int lane32 = threadIdx.x & 31;
  int row = blockIdx.x * 8 + sub;
  if (row >= nrows) return;
  int start = rowptr[row], end = rowptr[row + 1];
  float acc = 0.f;
  int j = start;
  for (; j + 3 < end; j += 4) {
    int2 e0 = cv[j];
    int2 e1 = cv[j + 1];
    int2 e2 = cv[j + 2];
    int2 e3 = cv[j + 3];
    float s0 = S2[(size_t)e0.x * 32 + lane32];
    float s1 = S2[(size_t)e1.x * 32 + lane32];
    float s2 = S2[(size_t)e2.x * 32 + lane32];
    float s3 = S2[(size_t)e3.x * 32 + lane32];
    acc += __int_as_float(e0.y) * s0;
    acc += __int_as_float(e1.y) * s1;
    acc += __int_as_float(e2.y) * s2;
    acc += __int_as_float(e3.y) * s3;
  }
  for (; j < end; j++) {
    int2 e0 = cv[j];
    acc += __int_as_float(e0.y) * S2[(size_t)e0.x * 32 + lane32];
  }
  float h = fmaxf(acc + bf[lane32], 0.f);
  float z0p = h * fc2W[lane32 * 2 + 0];
  float z1p = h * fc2W[lane32 * 2 + 1];
  #pragma unroll
  for (int m = 16; m >= 1; m >>= 1) {
    z0p += __shfl_xor(z0p, m, 32);
    z1p += __shfl_xor(z1p, m, 32);
  }
  if (lane32 == 0) {
    float z0 = z0p + fc2b[0];
    float z1 = z1p + fc2b[1];
    float mx = fmaxf(z0, z1);
    float lse = mx + logf(expf(z0 - mx) + expf(z1 - mx));
    float2 o = {z0 - lse, z1 - lse};
    *(float2*)(out + (size_t)row * 2) = o;
  }
}

// ---------------------------------------------------------------------------
extern "C" void kernel_launch(void* const* d_in, const int* in_sizes, int n_in,
                              void* d_out, int out_size, void* d_ws, size_t ws_size,
                              hipStream_t stream) {
  const float* X     = (const float*)d_in[0];
  const int*   erow  = (const int*)d_in[1];
  const int*   ecol  = (const int*)d_in[2];
  const float* eval_ = (const float*)d_in[3];
  const float* W1    = (const float*)d_in[4];
  const float* b1    = (const float*)d_in[5];
  const float* W2    = (const float*)d_in[6];
  const float* b2    = (const float*)d_in[7];
  const float* fc1W  = (const float*)d_in[8];
  const float* fc1b  = (const float*)d_in[9];
  const float* fc2W  = (const float*)d_in[10];
  const float* fc2b  = (const float*)d_in[11];
  float* out = (float*)d_out;

  size_t off = 0;
  auto alloc = [&](size_t bytes) {
    void* p = (char*)d_ws + off;
    off += (bytes + 255) & ~(size_t)255;
    return p;
  };
  ushort* WfTb   = (ushort*)alloc((size_t)HID * 32 * 2);
  float*  bf     = (float*)alloc(32 * 4);
  int*    cnt    = (int*)alloc((size_t)N_NODES * 4);
  int*    rowptr = (int*)alloc((size_t)(N_NODES + 1) * 4);
  int*    cursor = (int*)alloc((size_t)(N_NODES + 1) * 4);
  int*    bsum   = (int*)alloc((size_t)512 * 4);
  int*    bcur8  = (int*)alloc((size_t)64 * 4);
  int2*   cv     = (int2*)alloc((size_t)N_EDGES * 8);
  int2*   tcv    = (int2*)alloc((size_t)NB8 * BCAP * 8);
  int*    trow   = (int*)alloc((size_t)NB8 * BCAP * 4);
  ushort* W1T    = (ushort*)alloc((size_t)HID * IN_DIM * 2);
  ushort* S1b    = (ushort*)alloc((size_t)N_NODES * HID * 2);
  float*  S2     = (float*)alloc((size_t)N_NODES * 32 * 4);
  (void)ws_size; (void)n_in; (void)in_sizes; (void)out_size;

  const int NBLK = (N_NODES + 255) / 256;            // 391
  const int NCHUNK = (N_EDGES + CHUNK - 1) / CHUNK;  // 782

  hipMemsetAsync(cnt, 0, (size_t)N_NODES * 4, stream);

  fuse_weights<<<8, 256, 0, stream>>>(W2, fc1W, b2, fc1b, WfTb, bf);
  prep_w1t<<<HID, 256, 0, stream>>>(W1, W1T);

  hist_kernel<<<(N_EDGES + 255) / 256, 256, 0, stream>>>(erow, cnt, N_EDGES);
  blocksum_kernel<<<NBLK, 256, 0, stream>>>(cnt, bsum, N_NODES);
  scanpart_kernel<<<1, 512, 0, stream>>>(bsum, NBLK);
  scanfinal_kernel<<<NBLK, 256, 0, stream>>>(cnt, bsum, rowptr, cursor, N_NODES);
  bcur8_init<<<1, 64, 0, stream>>>(bcur8);
  scatter_p1<<<NCHUNK, 256, 0, stream>>>(
      erow, ecol, eval_, bcur8, tcv, trow, N_EDGES);
  scatter_p2<<<NB8 * NSLICE, 256, 0, stream>>>(bcur8, tcv, trow, cursor, cv);

  gemm1_mfma<<<(N_NODES + 127) / 128, 256, 0, stream>>>(X, W1T, S1b, N_NODES);

  spmm_fused<<<(N_NODES + 7) / 8, 512, 0, stream>>>(
      rowptr, cv, S1b, b1, WfTb, S2, N_NODES);

  spmm32_out_kernel<<<(N_NODES + 7) / 8, 256, 0, stream>>>(
      rowptr, cv, S2, bf, fc2W, fc2b, out, N_NODES);
}

// Round 6
// 960.020 us; speedup vs baseline: 1.8521x; 1.0402x over previous
//
#include <hip/hip_runtime.h>
#include <hip/hip_bf16.h>
#include <math.h>

#define N_NODES 100000
#define N_EDGES 3200000
#define IN_DIM  512
#define HID     256

#define NB8     8          // XCD-aligned row buckets
#define ROWS_PB 12500      // rows per bucket
#define BCAP    420000     // slots per bucket region
#define CHUNK   4096       // edges per phase-1 workgroup
#define NSLICE  96         // phase-2 slices per bucket
#define WFT_S   260        // WfT LDS stride in ushorts

typedef __attribute__((ext_vector_type(8))) short bf16x8;
typedef __attribute__((ext_vector_type(4))) float f32x4;

__device__ __forceinline__ ushort f2bf(float f) {
  uint x = __float_as_uint(f);
  return (ushort)((x + 0x7fffu + ((x >> 16) & 1u)) >> 16);
}
__device__ __forceinline__ float bf2f(ushort u) {
  return __uint_as_float(((uint)u) << 16);
}
// packed pair: lo element, hi element of a uint holding 2 bf16
__device__ __forceinline__ float bflo(uint u) { return __uint_as_float(u << 16); }
__device__ __forceinline__ float bfhi(uint u) { return __uint_as_float(u & 0xFFFF0000u); }

// ---------------------------------------------------------------------------
// K0: WfTb[j][k] = bf16( (W2 @ fc1_W)^T ), bfused = b2@fc1_W + fc1_b; bcur8 init
__global__ __launch_bounds__(256) void fuse_weights(
    const float* __restrict__ W2, const float* __restrict__ fc1W,
    const float* __restrict__ b2, const float* __restrict__ fc1b,
    ushort* __restrict__ WfTb, float* __restrict__ bf,
    int* __restrict__ bcur8) {
  int tid = threadIdx.x;
  int i = blockIdx.x * 32 + (tid >> 3);   // k index 0..255
  int jg = (tid & 7) * 4;                 // j group
  float4 acc = {0.f, 0.f, 0.f, 0.f};
  for (int k = 0; k < HID; k++) {
    float w = W2[i * HID + k];
    float4 f = *(const float4*)(fc1W + k * 32 + jg);
    acc.x += w * f.x; acc.y += w * f.y; acc.z += w * f.z; acc.w += w * f.w;
  }
  WfTb[(jg + 0) * HID + i] = f2bf(acc.x);
  WfTb[(jg + 1) * HID + i] = f2bf(acc.y);
  WfTb[(jg + 2) * HID + i] = f2bf(acc.z);
  WfTb[(jg + 3) * HID + i] = f2bf(acc.w);
  if (blockIdx.x == 0 && tid < 32) {
    float s = fc1b[tid];
    for (int k = 0; k < HID; k++) s += b2[k] * fc1W[k * 32 + tid];
    bf[tid] = s;
  }
  if (blockIdx.x == 1 && tid < NB8) bcur8[tid] = tid * BCAP;
}

// ---------------------------------------------------------------------------
// K0b: W1T_bf16[n][k] = bf16(W1[k][n])
__global__ __launch_bounds__(256) void prep_w1t(
    const float* __restrict__ W1, ushort* __restrict__ W1T) {
  int n = blockIdx.x;
  for (int k = threadIdx.x; k < IN_DIM; k += 256)
    W1T[(size_t)n * IN_DIM + k] = f2bf(W1[(size_t)k * HID + n]);
}

// ---------------------------------------------------------------------------
// K2a: per-block sums of cnt
__global__ __launch_bounds__(256) void blocksum_kernel(
    const int* __restrict__ cnt, int* __restrict__ bsum, int n) {
  int i = blockIdx.x * 256 + threadIdx.x;
  int v = (i < n) ? cnt[i] : 0;
  #pragma unroll
  for (int m = 1; m < 64; m <<= 1) v += __shfl_xor(v, m, 64);
  __shared__ int ws[4];
  if ((threadIdx.x & 63) == 0) ws[threadIdx.x >> 6] = v;
  __syncthreads();
  if (threadIdx.x == 0) bsum[blockIdx.x] = ws[0] + ws[1] + ws[2] + ws[3];
}

// K2b: exclusive scan of <=512 block sums
__global__ __launch_bounds__(512) void scanpart_kernel(
    int* __restrict__ bsum, int nb) {
  int tid = threadIdx.x, lane = tid & 63, wid = tid >> 6;
  int v = (tid < nb) ? bsum[tid] : 0;
  int x = v;
  #pragma unroll
  for (int d = 1; d < 64; d <<= 1) {
    int y = __shfl_up(x, d, 64);
    if (lane >= d) x += y;
  }
  __shared__ int ws[8];
  if (lane == 63) ws[wid] = x;
  __syncthreads();
  int woff = 0;
  for (int w = 0; w < wid; w++) woff += ws[w];
  if (tid < nb) bsum[tid] = woff + x - v;
}

// K2c: rowptr + cursor = bsum[block] + in-block exclusive scan
__global__ __launch_bounds__(256) void scanfinal_kernel(
    const int* __restrict__ cnt, const int* __restrict__ bsum,
    int* __restrict__ rowptr, int* __restrict__ cursor, int n) {
  int tid = threadIdx.x, lane = tid & 63, wid = tid >> 6;
  int i = blockIdx.x * 256 + tid;
  int v = (i < n) ? cnt[i] : 0;
  int x = v;
  #pragma unroll
  for (int d = 1; d < 64; d <<= 1) {
    int y = __shfl_up(x, d, 64);
    if (lane >= d) x += y;
  }
  __shared__ int ws[4];
  if (lane == 63) ws[wid] = x;
  __syncthreads();
  int woff = bsum[blockIdx.x];
  for (int w = 0; w < wid; w++) woff += ws[w];
  int excl = woff + x - v;
  if (i < n) { rowptr[i] = excl; cursor[i] = excl; }
  if (i == 0) rowptr[n] = N_EDGES;
}

// ---------------------------------------------------------------------------
// K3b: phase-1 — bin edges into 8 XCD-aligned buckets + histogram (fused).
__global__ __launch_bounds__(256) void scatter_p1(
    const int* __restrict__ rows, const int* __restrict__ cols,
    const float* __restrict__ vals, int* __restrict__ bcur8,
    int2* __restrict__ tcv, int* __restrict__ trow,
    int* __restrict__ cnt, int n) {
  __shared__ int bcnt[NB8];
  __shared__ int bcur[NB8];
  int tid = threadIdx.x;
  int chunk0 = blockIdx.x * CHUNK;
  if (tid < NB8) bcnt[tid] = 0;
  __syncthreads();

  int r[16], c[16], b[16];
  float v[16];
  #pragma unroll
  for (int i = 0; i < 16; i++) {
    int idx = chunk0 + i * 256 + tid;
    if (idx < n) {
      r[i] = rows[idx];
      c[i] = cols[idx];
      v[i] = vals[idx];
      b[i] = r[i] / ROWS_PB;
      atomicAdd(&bcnt[b[i]], 1);
      atomicAdd(&cnt[r[i]], 1);          // fused histogram
    } else {
      b[i] = -1;
    }
  }
  __syncthreads();
  if (tid < NB8) bcur[tid] = atomicAdd(&bcur8[tid], bcnt[tid]);
  __syncthreads();
  #pragma unroll
  for (int i = 0; i < 16; i++) {
    if (b[i] >= 0) {
      int p = atomicAdd(&bcur[b[i]], 1);
      trow[p] = r[i];
      int2 e; e.x = c[i]; e.y = __float_as_int(v[i]);
      tcv[p] = e;
    }
  }
}

// K3c: phase-2 — per-bucket scatter to final CSR, bucket pinned to XCD.
__global__ __launch_bounds__(256) void scatter_p2(
    const int* __restrict__ bcur8, const int2* __restrict__ tcv,
    const int* __restrict__ trow, int* __restrict__ cursor,
    int2* __restrict__ cv) {
  int b = blockIdx.x & 7;
  int s = blockIdx.x >> 3;
  int base = b * BCAP;
  int ecnt = bcur8[b] - base;
  int per = (ecnt + NSLICE - 1) / NSLICE;
  int lo = s * per;
  int hi = min(ecnt, lo + per);
  for (int i = base + lo + threadIdx.x; i < base + hi; i += 256) {
    int r = trow[i];
    int2 e = tcv[i];
    int p = atomicAdd(&cursor[r], 1);
    cv[p] = e;
  }
}

// ---------------------------------------------------------------------------
// K4: S1_bf16 = bf16( X @ W1 )  MFMA 16x16x32 bf16. BM=128 BN=256 BK=32.
__global__ __launch_bounds__(256) void gemm1_mfma(
    const float* __restrict__ A, const ushort* __restrict__ BT,
    ushort* __restrict__ C, int M) {
  __shared__ __align__(16) char smem[65536];
  ushort* As = (ushort*)smem;              // [128][40]
  ushort* Bs = (ushort*)(smem + 10240);    // [256][40]
  int tid = threadIdx.x;
  int bm = blockIdx.x * 128;
  int lane = tid & 63, wid = tid >> 6;
  int waveM = wid >> 1, waveN = wid & 1;
  int l16 = lane & 15, quad = lane >> 4;

  f32x4 acc[4][8] = {};

  int ar = tid >> 1;
  int ac = (tid & 1) * 16;
  const float* aptr = A + (size_t)(bm + ar) * IN_DIM + ac;
  bool avalid = (bm + ar) < M;
  ushort* aw = As + ar * 40 + ac;
  const ushort* bptr = BT + (size_t)tid * IN_DIM;
  ushort* bw = Bs + tid * 40;

  for (int k0 = 0; k0 < IN_DIM; k0 += 32) {
    #pragma unroll
    for (int i = 0; i < 4; i++) {
      float4 av = {0.f, 0.f, 0.f, 0.f};
      if (avalid) av = *(const float4*)(aptr + k0 + i * 4);
      ushort4 p;
      p.x = f2bf(av.x); p.y = f2bf(av.y); p.z = f2bf(av.z); p.w = f2bf(av.w);
      *(ushort4*)(aw + i * 4) = p;
    }
    #pragma unroll
    for (int i = 0; i < 4; i++)
      *(int4*)(bw + i * 8) = *(const int4*)(bptr + k0 + i * 8);
    __syncthreads();

    bf16x8 af[4], bfv[8];
    #pragma unroll
    for (int mi = 0; mi < 4; mi++)
      af[mi] = *(const bf16x8*)(As + (waveM * 64 + mi * 16 + l16) * 40 + quad * 8);
    #pragma unroll
    for (int ni = 0; ni < 8; ni++)
      bfv[ni] = *(const bf16x8*)(Bs + (waveN * 128 + ni * 16 + l16) * 40 + quad * 8);
    #pragma unroll
    for (int mi = 0; mi < 4; mi++)
      #pragma unroll
      for (int ni = 0; ni < 8; ni++)
        acc[mi][ni] = __builtin_amdgcn_mfma_f32_16x16x32_bf16(
            af[mi], bfv[ni], acc[mi][ni], 0, 0, 0);
    __syncthreads();
  }

  ushort* Cs = (ushort*)smem;   // [128][256]
  #pragma unroll
  for (int mi = 0; mi < 4; mi++)
    #pragma unroll
    for (int ni = 0; ni < 8; ni++)
      #pragma unroll
      for (int r = 0; r < 4; r++)
        Cs[(waveM * 64 + mi * 16 + quad * 4 + r) * 256 + waveN * 128 + ni * 16 + l16] =
            f2bf(acc[mi][ni][r]);
  __syncthreads();
  #pragma unroll
  for (int i = 0; i < 16; i++) {
    int f = tid + i * 256;
    int r = f >> 5, v8 = f & 31;
    if (bm + r < M)
      *(int4*)(C + (size_t)(bm + r) * HID + v8 * 8) =
          *(const int4*)(Cs + r * 256 + v8 * 8);
  }
}

// ---------------------------------------------------------------------------
// K5: fused: h = relu(A_sp @ S1 + b1) in LDS (fp32); S2_bf16 = h @ Wf.
// Packed bf16->f32 cvt (1 bit-op/elem) + float2 accums (v_pk_fma_f32).
__global__ __launch_bounds__(512, 8) void spmm_fused(
    const int* __restrict__ rowptr, const int2* __restrict__ cv,
    const ushort* __restrict__ S, const float* __restrict__ bias,
    const ushort* __restrict__ WfTb, ushort* __restrict__ S2b, int nrows) {
  __shared__ ushort WfT[32 * WFT_S];   // 16.25 KB bf16, [j][k]
  __shared__ float hbuf[8][256];       // 8 KB
  int tid = threadIdx.x;
  for (int idx = tid; idx < 32 * 64; idx += 512) {
    int jj = idx >> 6, kg = idx & 63;
    *(ushort4*)&WfT[jj * WFT_S + kg * 4] = *(const ushort4*)&WfTb[jj * HID + kg * 4];
  }
  __syncthreads();

  int w = tid >> 6, lane = tid & 63;
  int row = blockIdx.x * 8 + w;
  if (row >= nrows) return;
  int start = rowptr[row], end = rowptr[row + 1];
  float2 A01 = {0.f, 0.f}, A23 = {0.f, 0.f};
  const ushort* Sl = S + lane * 4;
  int j = start;
  for (; j + 3 < end; j += 4) {
    int2 e0 = cv[j];
    int2 e1 = cv[j + 1];
    int2 e2 = cv[j + 2];
    int2 e3 = cv[j + 3];
    uint2 u0 = *(const uint2*)(Sl + (size_t)e0.x * HID);
    uint2 u1 = *(const uint2*)(Sl + (size_t)e1.x * HID);
    uint2 u2 = *(const uint2*)(Sl + (size_t)e2.x * HID);
    uint2 u3 = *(const uint2*)(Sl + (size_t)e3.x * HID);
    float v0 = __int_as_float(e0.y);
    float v1 = __int_as_float(e1.y);
    float v2 = __int_as_float(e2.y);
    float v3 = __int_as_float(e3.y);
    A01.x += v0 * bflo(u0.x); A01.y += v0 * bfhi(u0.x);
    A23.x += v0 * bflo(u0.y); A23.y += v0 * bfhi(u0.y);
    A01.x += v1 * bflo(u1.x); A01.y += v1 * bfhi(u1.x);
    A23.x += v1 * bflo(u1.y); A23.y += v1 * bfhi(u1.y);
    A01.x += v2 * bflo(u2.x); A01.y += v2 * bfhi(u2.x);
    A23.x += v2 * bflo(u2.y); A23.y += v2 * bfhi(u2.y);
    A01.x += v3 * bflo(u3.x); A01.y += v3 * bfhi(u3.x);
    A23.x += v3 * bflo(u3.y); A23.y += v3 * bfhi(u3.y);
  }
  for (; j < end; j++) {
    int2 e0 = cv[j];
    float v0 = __int_as_float(e0.y);
    uint2 u0 = *(const uint2*)(Sl + (size_t)e0.x * HID);
    A01.x += v0 * bflo(u0.x); A01.y += v0 * bfhi(u0.x);
    A23.x += v0 * bflo(u0.y); A23.y += v0 * bfhi(u0.y);
  }
  float4 b = *(const float4*)(bias + lane * 4);
  float4 h;
  h.x = fmaxf(A01.x + b.x, 0.f);
  h.y = fmaxf(A01.y + b.y, 0.f);
  h.z = fmaxf(A23.x + b.z, 0.f);
  h.w = fmaxf(A23.y + b.w, 0.f);
  *(float4*)(&hbuf[w][lane * 4]) = h;
  // same-wave producer->consumer; compiler orders via lgkmcnt

  int jo = lane & 31;
  int kbase = (lane >> 5) * 128;
  const float* hb = &hbuf[w][kbase];
  const ushort* wt = &WfT[jo * WFT_S + kbase];
  float2 acc2 = {0.f, 0.f};
  #pragma unroll
  for (int kk = 0; kk < 32; kk++) {
    float4 hv = *(const float4*)(hb + kk * 4);       // broadcast (free)
    uint2 wv = *(const uint2*)(wt + kk * 4);         // b64, <=4-way
    acc2.x += hv.x * bflo(wv.x) + hv.z * bflo(wv.y);
    acc2.y += hv.y * bfhi(wv.x) + hv.w * bfhi(wv.y);
  }
  float acc = acc2.x + acc2.y;
  acc += __shfl_xor(acc, 32, 64);
  if (lane < 32) S2b[(size_t)row * 32 + jo] = f2bf(acc);
}

// ---------------------------------------------------------------------------
// K7: t = A_sp @ S2 + bfused; out = log_softmax(relu(t) @ fc2W + fc2b)
// 16-lane row groups (2 features/lane via packed bf16), 16 rows/block.
__global__ __launch_bounds__(256) void spmm32_out_kernel(
    const int* __restrict__ rowptr, const int2* __restrict__ cv,
    const ushort* __restrict__ S2b, const float* __restrict__ bf,
    const float* __restrict__ fc2W, const float* __restrict__ fc2b,
    float* __restrict__ out, int nrows) {
  int sub = threadIdx.x >> 4;          // 0..15
  int l16 = threadIdx.x & 15;
  int row = blockIdx.x * 16 + sub;
  if (row >= nrows) return;
  int start = rowptr[row], end = rowptr[row + 1];
  float a0 = 0.f, a1 = 0.f;            // features 2*l16, 2*l16+1
  const ushort* Sl = S2b + l16 * 2;
  int j = start;
  for (; j + 3 < end; j += 4) {
    int2 e0 = cv[j];
    int2 e1 = cv[j + 1];
    int2 e2 = cv[j + 2];
    int2 e3 = cv[j + 3];
    uint u0 = *(const uint*)(Sl + (size_t)e0.x * 32);
    uint u1 = *(const uint*)(Sl + (size_t)e1.x * 32);
    uint u2 = *(const uint*)(Sl + (size_t)e2.x * 32);
    uint u3 = *(const uint*)(Sl + (size_t)e3.x * 32);
    float v0 = __int_as_float(e0.y);
    float v1 = __int_as_float(e1.y);
    float v2 = __int_as_float(e2.y);
    float v3 = __int_as_float(e3.y);
    a0 += v0 * bflo(u0); a1 += v0 * bfhi(u0);
    a0 += v1 * bflo(u1); a1 += v1 * bfhi(u1);
    a0 += v2 * bflo(u2); a1 += v2 * bfhi(u2);
    a0 += v3 * bflo(u3); a1 += v3 * bfhi(u3);
  }
  for (; j < end; j++) {
    int2 e0 = cv[j];
    float v0 = __int_as_float(e0.y);
    uint u0 = *(const uint*)(Sl + (size_t)e0.x * 32);
    a0 += v0 * bflo(u0); a1 += v0 * bfhi(u0);
  }
  int k0 = l16 * 2, k1 = l16 * 2 + 1;
  float h0 = fmaxf(a0 + bf[k0], 0.f);
  float h1 = fmaxf(a1 + bf[k1], 0.f);
  float z0p = h0 * fc2W[k0 * 2 + 0] + h1 * fc2W[k1 * 2 + 0];
  float z1p = h0 * fc2W[k0 * 2 + 1] + h1 * fc2W[k1 * 2 + 1];
  #pragma unroll
  for (int m = 8; m >= 1; m >>= 1) {
    z0p += __shfl_xor(z0p, m, 16);
    z1p += __shfl_xor(z1p, m, 16);
  }
  if (l16 == 0) {
    float z0 = z0p + fc2b[0];
    float z1 = z1p + fc2b[1];
    float mx = fmaxf(z0, z1);
    float lse = mx + logf(expf(z0 - mx) + expf(z1 - mx));
    float2 o = {z0 - lse, z1 - lse};
    *(float2*)(out + (size_t)row * 2) = o;
  }
}

// ---------------------------------------------------------------------------
extern "C" void kernel_launch(void* const* d_in, const int* in_sizes, int n_in,
                              void* d_out, int out_size, void* d_ws, size_t ws_size,
                              hipStream_t stream) {
  const float* X     = (const float*)d_in[0];
  const int*   erow  = (const int*)d_in[1];
  const int*   ecol  = (const int*)d_in[2];
  const float* eval_ = (const float*)d_in[3];
  const float* W1    = (const float*)d_in[4];
  const float* b1    = (const float*)d_in[5];
  const float* W2    = (const float*)d_in[6];
  const float* b2    = (const float*)d_in[7];
  const float* fc1W  = (const float*)d_in[8];
  const float* fc1b  = (const float*)d_in[9];
  const float* fc2W  = (const float*)d_in[10];
  const float* fc2b  = (const float*)d_in[11];
  float* out = (float*)d_out;

  size_t off = 0;
  auto alloc = [&](size_t bytes) {
    void* p = (char*)d_ws + off;
    off += (bytes + 255) & ~(size_t)255;
    return p;
  };
  ushort* WfTb   = (ushort*)alloc((size_t)HID * 32 * 2);
  float*  bf     = (float*)alloc(32 * 4);
  int*    cnt    = (int*)alloc((size_t)N_NODES * 4);
  int*    rowptr = (int*)alloc((size_t)(N_NODES + 1) * 4);
  int*    cursor = (int*)alloc((size_t)(N_NODES + 1) * 4);
  int*    bsum   = (int*)alloc((size_t)512 * 4);
  int*    bcur8  = (int*)alloc((size_t)64 * 4);
  int2*   cv     = (int2*)alloc((size_t)N_EDGES * 8);
  int2*   tcv    = (int2*)alloc((size_t)NB8 * BCAP * 8);
  int*    trow   = (int*)alloc((size_t)NB8 * BCAP * 4);
  ushort* W1T    = (ushort*)alloc((size_t)HID * IN_DIM * 2);
  ushort* S1b    = (ushort*)alloc((size_t)N_NODES * HID * 2);
  ushort* S2b    = (ushort*)alloc((size_t)N_NODES * 32 * 2);
  (void)ws_size; (void)n_in; (void)in_sizes; (void)out_size;

  const int NBLK = (N_NODES + 255) / 256;            // 391
  const int NCHUNK = (N_EDGES + CHUNK - 1) / CHUNK;  // 782

  hipMemsetAsync(cnt, 0, (size_t)N_NODES * 4, stream);

  fuse_weights<<<8, 256, 0, stream>>>(W2, fc1W, b2, fc1b, WfTb, bf, bcur8);
  prep_w1t<<<HID, 256, 0, stream>>>(W1, W1T);

  scatter_p1<<<NCHUNK, 256, 0, stream>>>(
      erow, ecol, eval_, bcur8, tcv, trow, cnt, N_EDGES);
  blocksum_kernel<<<NBLK, 256, 0, stream>>>(cnt, bsum, N_NODES);
  scanpart_kernel<<<1, 512, 0, stream>>>(bsum, NBLK);
  scanfinal_kernel<<<NBLK, 256, 0, stream>>>(cnt, bsum, rowptr, cursor, N_NODES);
  scatter_p2<<<NB8 * NSLICE, 256, 0, stream>>>(bcur8, tcv, trow, cursor, cv);

  gemm1_mfma<<<(N_NODES + 127) / 128, 256, 0, stream>>>(X, W1T, S1b, N_NODES);

  spmm_fused<<<(N_NODES + 7) / 8, 512, 0, stream>>>(
      rowptr, cv, S1b, b1, WfTb, S2b, N_NODES);

  spmm32_out_kernel<<<(N_NODES + 15) / 16, 256, 0, stream>>>(
      rowptr, cv, S2b, bf, fc2W, fc2b, out, N_NODES);
}